// Round 16
// baseline (243.436 us; speedup 1.0000x reference)
//
#include <hip/hip_runtime.h>
#include <math.h>

#define L 2048
#define CP 128
#define CH 512
#define NH 8
#define HD 64
#define RANKF 4
#define KS 4
#define KEYS (L / KS)

typedef __attribute__((ext_vector_type(8))) short bf16x8;
typedef __attribute__((ext_vector_type(4))) float f32x4;

// ws byte offsets
#define O_ZNS   0u         // [2048][128] bf16      512 KB
#define O_WTS   524288u    // [1536][128] bf16      384 KB  (Wq|Wk|Wv)^T
#define O_WGT   917504u    // [128][128]  bf16       32 KB  Wgate^T
#define O_WOTS  950272u    // [128][512]  bf16      128 KB  Wout^T
#define O_QS    1081344u   // [2048][512] bf16        2 MB
#define O_KS2   3178496u   // [2048][512] bf16        2 MB
#define O_VTS   5275648u   // [512][2048] bf16        2 MB
#define O_KB    7372800u   // [2048] f32              8 KB
#define O_PO    7380992u   // [4][2048][512] bf16     8 MB
#define O_PL    15769600u  // [4][8][2048] f32      256 KB
#define O_CNT   16031744u  // [16] int

__device__ __forceinline__ unsigned short f2bf(float f) {
  union { float f; unsigned u; } x; x.f = f;
  unsigned r = x.u + 0x7fffu + ((x.u >> 16) & 1u);
  return (unsigned short)(r >> 16);
}
__device__ __forceinline__ float bf2f(unsigned short h) {
  union { unsigned u; float f; } x; x.u = ((unsigned)h) << 16;
  return x.f;
}
__device__ __forceinline__ unsigned pack2bf(float lo, float hi) {
  return (unsigned)f2bf(lo) | ((unsigned)f2bf(hi) << 16);
}

// ---------------- K1: fused prep (LN | Wqkv^T | Wgate^T | Wout^T | cnt=0) ---
__global__ __launch_bounds__(256, 4)
void k_prep(const float* __restrict__ zl, const float* __restrict__ zr,
            const float* __restrict__ mask,
            const float* __restrict__ g, const float* __restrict__ b,
            const float* __restrict__ Wq, const float* __restrict__ Wk,
            const float* __restrict__ Wv, const float* __restrict__ Wg,
            const float* __restrict__ Wout,
            unsigned short* __restrict__ zn_s, float* __restrict__ kb,
            unsigned short* __restrict__ Wt_s, unsigned short* __restrict__ Wgt_s,
            unsigned short* __restrict__ Wot_s, int* __restrict__ cnt) {
  __shared__ float tile[128][33];
  __shared__ float red[8];
  int bid = blockIdx.x;
  int t = threadIdx.x;

  if (bid < 1024) {
    if (bid == 0 && t < 16) cnt[t] = 0;    // zero merge counters every call
    int half = t >> 7, c = t & 127;
    int l = bid * 2 + half;
    const float* zlrow = zl + (size_t)l * RANKF * CP;
    const float* zrrow = zr + (size_t)l * RANKF * CP;
    float z = 0.f;
#pragma unroll
    for (int r = 0; r < RANKF; ++r) z += zlrow[r * CP + c] + zrrow[r * CP + c];

    float s = z;
#pragma unroll
    for (int off = 32; off >= 1; off >>= 1) s += __shfl_xor(s, off, 64);
    if ((t & 63) == 0) red[t >> 6] = s;
    __syncthreads();
    float mu = (red[half * 2] + red[half * 2 + 1]) * (1.f / 128.f);
    float d = z - mu;
    float sq = d * d;
#pragma unroll
    for (int off = 32; off >= 1; off >>= 1) sq += __shfl_xor(sq, off, 64);
    if ((t & 63) == 0) red[4 + (t >> 6)] = sq;
    __syncthreads();
    float var = (red[4 + half * 2] + red[4 + half * 2 + 1]) * (1.f / 128.f);
    float rstd = rsqrtf(var + 1e-5f);
    float val = d * rstd * g[c] + b[c];
    zn_s[(size_t)l * CP + c] = f2bf(val);
    // key-bias pre-scaled by log2(e): exp(x)=exp2(x*log2e); mask==1 -> 0 exact
    if (c == 0) kb[l] = 1.4426950e9f * (mask[l] - 1.f);
    // Wbias: constant along softmax key axis -> cancels exactly; skipped.
  } else if (bid < 1072) {
    int c0 = (bid - 1024) * 32;
#pragma unroll
    for (int i = 0; i < 16; ++i) {
      int idx = i * 256 + t;
      int col = idx & 31, kk = idx >> 5;
      int gc = c0 + col;
      float w;
      if (gc < 512)       w = Wq[(size_t)kk * CH + gc];
      else if (gc < 1024) w = Wk[(size_t)kk * CH + gc - 512];
      else                w = Wv[(size_t)kk * CH + gc - 1024];
      tile[kk][col] = w;
    }
    __syncthreads();
#pragma unroll
    for (int i = 0; i < 16; ++i) {
      int idx = i * 256 + t;
      int kk = idx & 127, col = idx >> 7;
      Wt_s[(size_t)(c0 + col) * 128 + kk] = f2bf(tile[kk][col]);
    }
  } else if (bid < 1076) {
    int c0 = (bid - 1072) * 32;
#pragma unroll
    for (int i = 0; i < 16; ++i) {
      int idx = i * 256 + t;
      int col = idx & 31, kk = idx >> 5;
      tile[kk][col] = Wg[(size_t)kk * CP + c0 + col];
    }
    __syncthreads();
#pragma unroll
    for (int i = 0; i < 16; ++i) {
      int idx = i * 256 + t;
      int kk = idx & 127, col = idx >> 7;
      Wgt_s[(size_t)(c0 + col) * 128 + kk] = f2bf(tile[kk][col]);
    }
  } else {
    int bx = bid - 1076;
    int c0 = (bx & 3) * 32, k0 = (bx >> 2) * 128;
#pragma unroll
    for (int i = 0; i < 16; ++i) {
      int idx = i * 256 + t;
      int col = idx & 31, kk = idx >> 5;
      tile[kk][col] = Wout[(size_t)(k0 + kk) * CP + c0 + col];
    }
    __syncthreads();
#pragma unroll
    for (int i = 0; i < 16; ++i) {
      int idx = i * 256 + t;
      int kk = idx & 127, col = idx >> 7;
      Wot_s[(size_t)(c0 + col) * 512 + k0 + kk] = f2bf(tile[kk][col]);
    }
  }
}

// ---------------- K2: QKV projection, 1-pass bf16 MFMA ----------------------
__global__ __launch_bounds__(256, 4)
void k_proj(const unsigned short* __restrict__ zn_s, const unsigned short* __restrict__ Wt_s,
            const float* __restrict__ bq, const float* __restrict__ bk,
            const float* __restrict__ bv,
            unsigned short* __restrict__ q_s, unsigned short* __restrict__ k_s,
            unsigned short* __restrict__ vt_s) {
  __shared__ unsigned short vtile[128][65];
  int t = threadIdx.x, wid = t >> 6, lane = t & 63, li = lane & 15, g = lane >> 4;
  int cb = blockIdx.x;
  int c0 = cb * 128;
  int rb = blockIdx.y * 64;
  int arow = rb + wid * 16 + li;

  f32x4 acc[8];
#pragma unroll
  for (int i = 0; i < 8; ++i) acc[i] = (f32x4){0.f, 0.f, 0.f, 0.f};

  const unsigned short* ap = zn_s + (size_t)arow * CP;
#pragma unroll
  for (int s = 0; s < 4; ++s) {
    bf16x8 af = *(const bf16x8*)(ap + s * 32 + g * 8);
#pragma unroll
    for (int tt = 0; tt < 8; ++tt) {
      int col = c0 + tt * 16 + li;
      bf16x8 bfr = *(const bf16x8*)(Wt_s + (size_t)col * 128 + s * 32 + g * 8);
      acc[tt] = __builtin_amdgcn_mfma_f32_16x16x32_bf16(af, bfr, acc[tt], 0, 0, 0);
    }
  }

  int mode = cb >> 2;  // 0=q 1=k 2=v
  if (mode == 2) {
#pragma unroll
    for (int tt = 0; tt < 8; ++tt) {
      int colL = tt * 16 + li;
      float bb = bv[c0 - 1024 + colL];
#pragma unroll
      for (int r = 0; r < 4; ++r)
        vtile[colL][wid * 16 + g * 4 + r] = f2bf(acc[tt][r] + bb);
    }
    __syncthreads();
#pragma unroll
    for (int i = 0; i < 32; ++i) {
      int idx = i * 256 + t;
      int colL = idx >> 6, rowL = idx & 63;
      vt_s[(size_t)(c0 - 1024 + colL) * L + rb + rowL] = vtile[colL][rowL];
    }
  } else {
#pragma unroll
    for (int tt = 0; tt < 8; ++tt) {
      int col = c0 + tt * 16 + li;
#pragma unroll
      for (int r = 0; r < 4; ++r) {
        int orow = rb + wid * 16 + g * 4 + r;
        float val = acc[tt][r];
        if (mode == 0) {
          // fold 0.125*log2(e) into Q (bf16 rounding is scale-invariant)
          q_s[(size_t)orow * CH + col] = f2bf((val + bq[col]) * 0.18033688f);
        } else {
          k_s[(size_t)orow * CH + col - 512] = f2bf(val + bk[col - 512]);
        }
      }
    }
  }
}

// ---------------- K3: flash attention + fused merge/out epilogue ------------
// QB=128: 8 waves x 16 q-rows; grid 8x16x4 = 512 blocks; 4 barriers/block
#define QB 128
#define KTILE 128
#define NTT (KEYS / KTILE)
#define LK0  0
#define LK1  16384
#define LVT0 32768
#define LVT1 49152
#define LP   65536     // 8 waves x 2048B = 16 KB; total LDS 80 KB

__global__ __launch_bounds__(512, 4)
void k_attn(const unsigned short* __restrict__ qg, const unsigned short* __restrict__ kg,
            const unsigned short* __restrict__ vtg, const float* __restrict__ kbias,
            unsigned short* __restrict__ po, float* __restrict__ pl,
            const unsigned short* __restrict__ Wot_s, const float* __restrict__ bout,
            const unsigned short* __restrict__ zn_s, const unsigned short* __restrict__ Wgt_s,
            const float* __restrict__ bg, int* __restrict__ cnt,
            float* __restrict__ out) {
  __shared__ __align__(16) unsigned char lds[81920];
  int h = blockIdx.x, qblk = blockIdx.y, ksp = blockIdx.z;
  int tid = threadIdx.x, wid = tid >> 6, lane = tid & 63;
  int li = lane & 15, g = lane >> 4;
  int q0 = qblk * QB, hbase = h * HD, kbase = ksp * KEYS;

  bf16x8 aq[2];
  {
    const unsigned short* qp = qg + (size_t)(q0 + wid * 16 + li) * CH + hbase + g * 8;
    aq[0] = *(const bf16x8*)(qp);
    aq[1] = *(const bf16x8*)(qp + 32);
  }

  float lsum = 0.f;
  f32x4 o[4];
#pragma unroll
  for (int t2 = 0; t2 < 4; ++t2) o[t2] = (f32x4){0.f, 0.f, 0.f, 0.f};

  auto stage = [&](int buf, int kt) {
    int k0 = kbase + kt * KTILE;
    int row = tid >> 3, c16 = tid & 7;
#pragma unroll
    for (int hh = 0; hh < 2; ++hh) {
      const unsigned short* gpk = kg + (size_t)(k0 + hh * 64 + row) * CH + hbase + ((c16 ^ (row & 7)) << 3);
      __builtin_amdgcn_global_load_lds(
          (const __attribute__((address_space(1))) unsigned int*)(gpk),
          (__attribute__((address_space(3))) unsigned int*)(lds + (buf ? LK1 : LK0) + hh * 8192 + wid * 1024),
          16, 0, 0);
      const unsigned short* gpv = vtg + (size_t)(hbase + row) * L + k0 + hh * 64 + ((c16 ^ (row & 7)) << 3);
      __builtin_amdgcn_global_load_lds(
          (const __attribute__((address_space(1))) unsigned int*)(gpv),
          (__attribute__((address_space(3))) unsigned int*)(lds + (buf ? LVT1 : LVT0) + hh * 8192 + wid * 1024),
          16, 0, 0);
    }
  };

  stage(0, 0);
  __syncthreads();

  for (int kt = 0; kt < NTT; ++kt) {
    int buf = kt & 1;
    if (kt + 1 < NTT) stage(buf ^ 1, kt + 1);

    const unsigned char* Kb = lds + (buf ? LK1 : LK0);
    const unsigned char* Vb = lds + (buf ? LVT1 : LVT0);

#pragma unroll
    for (int hh = 0; hh < 2; ++hh) {
      int k0 = kbase + kt * KTILE + hh * 64;
      const unsigned char* Kbh = Kb + hh * 8192;
      const unsigned char* Vbh = Vb + hh * 8192;

      float4 kbv[4];
#pragma unroll
      for (int tt = 0; tt < 4; ++tt)
        kbv[tt] = *(const float4*)(kbias + k0 + tt * 16 + 4 * g);

      f32x4 s[4];
      __builtin_amdgcn_s_setprio(1);
#pragma unroll
      for (int tt = 0; tt < 4; ++tt) {
        int key = tt * 16 + li;
        f32x4 accs = (f32x4){0.f, 0.f, 0.f, 0.f};
#pragma unroll
        for (int h2 = 0; h2 < 2; ++h2) {
          int c16 = h2 * 4 + g;
          bf16x8 bk = *(const bf16x8*)(Kbh + key * 128 + ((c16 ^ (key & 7)) << 4));
          accs = __builtin_amdgcn_mfma_f32_16x16x32_bf16(bk, aq[h2], accs, 0, 0, 0);
        }
        s[tt] = accs;
      }
      __builtin_amdgcn_s_setprio(0);

      unsigned pk[4][2];
#pragma unroll
      for (int tt = 0; tt < 4; ++tt) {
        float e0 = exp2f(s[tt][0] + kbv[tt].x);
        float e1 = exp2f(s[tt][1] + kbv[tt].y);
        float e2 = exp2f(s[tt][2] + kbv[tt].z);
        float e3 = exp2f(s[tt][3] + kbv[tt].w);
        lsum += (e0 + e1) + (e2 + e3);
        pk[tt][0] = pack2bf(e0, e1);
        pk[tt][1] = pack2bf(e2, e3);
      }

      unsigned char* Pp = lds + LP + wid * 2048;
#pragma unroll
      for (int tt = 0; tt < 4; ++tt) {
#pragma unroll
        for (int p = 0; p < 2; ++p) {
          int boff = 32 * tt + 8 * g + 4 * p;
          int addr = li * 128 + ((((boff >> 4) ^ (li & 7)) << 4) | (boff & 15));
          *(unsigned*)(Pp + addr) = pk[tt][p];
        }
      }

      __builtin_amdgcn_s_setprio(1);
#pragma unroll
      for (int c = 0; c < 2; ++c) {
        int gran = 4 * c + g;
        bf16x8 pa = *(const bf16x8*)(Pp + li * 128 + ((gran ^ (li & 7)) << 4));
#pragma unroll
        for (int t2 = 0; t2 < 4; ++t2) {
          int d = t2 * 16 + li;
          bf16x8 bv2 = *(const bf16x8*)(Vbh + d * 128 + ((gran ^ (d & 7)) << 4));
          o[t2] = __builtin_amdgcn_mfma_f32_16x16x32_bf16(pa, bv2, o[t2], 0, 0, 0);
        }
      }
      __builtin_amdgcn_s_setprio(0);
    }

    __syncthreads();
  }

  // ---- partial epilogue: store normalized po + pl ----
  lsum += __shfl_xor(lsum, 16);
  lsum += __shfl_xor(lsum, 32);
  float rinv[4];
#pragma unroll
  for (int r = 0; r < 4; ++r) rinv[r] = 1.f / __shfl(lsum, 4 * g + r, 16);
#pragma unroll
  for (int t2 = 0; t2 < 4; ++t2) {
#pragma unroll
    for (int r = 0; r < 4; ++r) {
      int qrow = q0 + wid * 16 + 4 * g + r;
      po[((size_t)ksp * L + qrow) * CH + hbase + t2 * 16 + li] = f2bf(o[t2][r] * rinv[r]);
    }
  }
  if (g == 0) {
    int qrow = q0 + wid * 16 + li;
    pl[((size_t)ksp * NH + h) * L + qrow] = lsum;
  }

  // ---- completion signal: 32 contributors (8h x 4ksp) per qblk ----
  __threadfence();                       // release: drain + L2 writeback
  __syncthreads();                       // all threads' stores fenced
  volatile int* flag = (volatile int*)(lds + 81912);
  if (tid == 0) {
    int old = __hip_atomic_fetch_add(&cnt[qblk], 1, __ATOMIC_ACQ_REL,
                                     __HIP_MEMORY_SCOPE_AGENT);
    *flag = (old == 31);
  }
  __syncthreads();
  if (!*flag) return;

  // ---- merge + out-proj + gate + broadcast for rows q0..q0+127 ----
  // acquire per-thread: invalidate caches so po/pl stores from other XCDs
  // (and not last replay's values) are visible
  (void)__hip_atomic_load(&cnt[qblk], __ATOMIC_ACQUIRE, __HIP_MEMORY_SCOPE_AGENT);
  unsigned char* ab = lds;               // 16 rows x 512 cols bf16 = 16 KB

  for (int ch = 0; ch < 8; ++ch) {
    int rchunk = q0 + ch * 16;
    __syncthreads();                     // ab free from previous chunk

    // merge phase: wave w handles rows w*2, w*2+1; lane covers 8 cols
    int col8 = lane * 8;
    int h2 = col8 >> 6;
#pragma unroll
    for (int i = 0; i < 2; ++i) {
      int rowL = wid * 2 + i;
      int row = rchunk + rowL;
      float w[4], wsum = 0.f;
#pragma unroll
      for (int s2 = 0; s2 < 4; ++s2) {
        w[s2] = pl[((size_t)s2 * NH + h2) * L + row];
        wsum += w[s2];
      }
      float rv = 1.f / wsum;
      float accv[8];
#pragma unroll
      for (int j = 0; j < 8; ++j) accv[j] = 0.f;
#pragma unroll
      for (int s2 = 0; s2 < 4; ++s2) {
        bf16x8 pv = *(const bf16x8*)(po + ((size_t)s2 * L + row) * CH + col8);
        float ww = w[s2];
#pragma unroll
        for (int j = 0; j < 8; ++j) accv[j] += ww * bf2f((unsigned short)pv[j]);
      }
      bf16x8 packed;
#pragma unroll
      for (int j = 0; j < 8; ++j) packed[j] = (short)f2bf(accv[j] * rv);
      int byteoff = (rowL * 1024 + col8 * 2) ^ ((rowL & 7) << 4);
      *(bf16x8*)(ab + byteoff) = packed;
    }
    __syncthreads();

    // GEMM: out-proj (K=512) + gate (K=128); wave w covers cols [w*16,w*16+16)
    f32x4 acc = (f32x4){0.f, 0.f, 0.f, 0.f};
    f32x4 gacc = (f32x4){0.f, 0.f, 0.f, 0.f};
    int col = wid * 16 + li;
#pragma unroll
    for (int s = 0; s < 16; ++s) {
      int abyte = (li * 1024 + (s * 32 + g * 8) * 2) ^ ((li & 7) << 4);
      bf16x8 af = *(const bf16x8*)(ab + abyte);
      bf16x8 bfr = *(const bf16x8*)(Wot_s + (size_t)col * 512 + s * 32 + g * 8);
      acc = __builtin_amdgcn_mfma_f32_16x16x32_bf16(af, bfr, acc, 0, 0, 0);
    }
#pragma unroll
    for (int s = 0; s < 4; ++s) {
      bf16x8 af = *(const bf16x8*)(zn_s + (size_t)(rchunk + li) * CP + s * 32 + g * 8);
      bf16x8 bfr = *(const bf16x8*)(Wgt_s + (size_t)col * 128 + s * 32 + g * 8);
      gacc = __builtin_amdgcn_mfma_f32_16x16x32_bf16(af, bfr, gacc, 0, 0, 0);
    }

    float bb = bout[col];
    float gb = bg[col];
#pragma unroll
    for (int r = 0; r < 4; ++r) {
      int row = rchunk + g * 4 + r;
      float gatev = 1.f / (1.f + __expf(-(gacc[r] + gb)));
      float val = (acc[r] + bb) * gatev * 0.25f;
#pragma unroll
      for (int rk = 0; rk < 4; ++rk)
        out[(size_t)(row * 4 + rk) * CP + col] = val;
    }
    // zero out_right rows [rchunk*4, rchunk*4+64) x 128 f32 = 2048 float4
    float4 z = {0.f, 0.f, 0.f, 0.f};
    float4* orp = (float4*)(out + (size_t)L * RANKF * CP + (size_t)rchunk * 4 * CP);
#pragma unroll
    for (int i = 0; i < 4; ++i) orp[i * 512 + tid] = z;
  }
}

extern "C" void kernel_launch(void* const* d_in, const int* in_sizes, int n_in,
                              void* d_out, int out_size, void* d_ws, size_t ws_size,
                              hipStream_t stream) {
  const float* zl   = (const float*)d_in[0];
  const float* zr   = (const float*)d_in[1];
  const float* mask = (const float*)d_in[2];
  const float* lng  = (const float*)d_in[3];
  const float* lnb  = (const float*)d_in[4];
  const float* Wq   = (const float*)d_in[5];
  const float* bq   = (const float*)d_in[6];
  const float* Wk   = (const float*)d_in[7];
  const float* bk   = (const float*)d_in[8];
  const float* Wv   = (const float*)d_in[9];
  const float* bv   = (const float*)d_in[10];
  // d_in[11] = Wbias: softmax-invariant -> unused
  const float* Wout = (const float*)d_in[12];
  const float* bout = (const float*)d_in[13];
  const float* Wg   = (const float*)d_in[14];
  const float* bg   = (const float*)d_in[15];
  float* out = (float*)d_out;
  unsigned char* ws = (unsigned char*)d_ws;

  unsigned short* zn_s  = (unsigned short*)(ws + O_ZNS);
  unsigned short* Wt_s  = (unsigned short*)(ws + O_WTS);
  unsigned short* Wgt_s = (unsigned short*)(ws + O_WGT);
  unsigned short* Wot_s = (unsigned short*)(ws + O_WOTS);
  unsigned short* q_s   = (unsigned short*)(ws + O_QS);
  unsigned short* k_s   = (unsigned short*)(ws + O_KS2);
  unsigned short* vt_s  = (unsigned short*)(ws + O_VTS);
  float* kb   = (float*)(ws + O_KB);
  unsigned short* po = (unsigned short*)(ws + O_PO);
  float* pl   = (float*)(ws + O_PL);
  int* cnt    = (int*)(ws + O_CNT);

  k_prep<<<dim3(1092),       dim3(256), 0, stream>>>(zl, zr, mask, lng, lnb,
                                                     Wq, Wk, Wv, Wg, Wout,
                                                     zn_s, kb, Wt_s, Wgt_s, Wot_s, cnt);
  k_proj<<<dim3(12, 32),     dim3(256), 0, stream>>>(zn_s, Wt_s, bq, bk, bv,
                                                     q_s, k_s, vt_s);
  k_attn<<<dim3(NH, L/QB, KS), dim3(512), 0, stream>>>(q_s, k_s, vt_s, kb, po, pl,
                                                       Wot_s, bout, zn_s, Wgt_s, bg,
                                                       cnt, out);
}

// Round 17
// 59.916 us; speedup vs baseline: 4.0629x; 4.0629x over previous
//
#include <hip/hip_runtime.h>
#include <math.h>

#define L 2048
#define CP 128
#define CH 512
#define NH 8
#define HD 64
#define RANKF 4
#define KS 4
#define KEYS (L / KS)

typedef __attribute__((ext_vector_type(8))) short bf16x8;
typedef __attribute__((ext_vector_type(4))) float f32x4;

// ws byte offsets
#define O_ZNS   0u         // [2048][128] bf16      512 KB
#define O_WTS   524288u    // [1536][128] bf16      384 KB  (Wq|Wk|Wv)^T
#define O_WGT   917504u    // [128][128]  bf16       32 KB  Wgate^T
#define O_WOTS  950272u    // [128][512]  bf16      128 KB  Wout^T
#define O_QS    1081344u   // [2048][512] bf16        2 MB
#define O_KS2   3178496u   // [2048][512] bf16        2 MB
#define O_VTS   5275648u   // [512][2048] bf16        2 MB
#define O_KB    7372800u   // [2048] f32              8 KB
#define O_PO    7380992u   // [4][2048][512] bf16     8 MB
#define O_PL    15769600u  // [4][8][2048] f32      256 KB

__device__ __forceinline__ unsigned short f2bf(float f) {
  union { float f; unsigned u; } x; x.f = f;
  unsigned r = x.u + 0x7fffu + ((x.u >> 16) & 1u);
  return (unsigned short)(r >> 16);
}
__device__ __forceinline__ float bf2f(unsigned short h) {
  union { unsigned u; float f; } x; x.u = ((unsigned)h) << 16;
  return x.f;
}
__device__ __forceinline__ unsigned pack2bf(float lo, float hi) {
  return (unsigned)f2bf(lo) | ((unsigned)f2bf(hi) << 16);
}

// ---------------- K1: fused prep (LN | Wqkv^T | Wgate^T | Wout^T) -----------
// grid: [0,1024) LN 2 rows | [1024,1072) Wqkv | [1072,1076) Wgate | [1076,1092) Wout
__global__ __launch_bounds__(256, 4)
void k_prep(const float* __restrict__ zl, const float* __restrict__ zr,
            const float* __restrict__ mask,
            const float* __restrict__ g, const float* __restrict__ b,
            const float* __restrict__ Wq, const float* __restrict__ Wk,
            const float* __restrict__ Wv, const float* __restrict__ Wg,
            const float* __restrict__ Wout,
            unsigned short* __restrict__ zn_s, float* __restrict__ kb,
            unsigned short* __restrict__ Wt_s, unsigned short* __restrict__ Wgt_s,
            unsigned short* __restrict__ Wot_s) {
  __shared__ float tile[128][33];
  __shared__ float red[8];
  int bid = blockIdx.x;
  int t = threadIdx.x;

  if (bid < 1024) {
    // -------- LayerNorm, 2 rows per block; bf16 output --------
    int half = t >> 7, c = t & 127;
    int l = bid * 2 + half;
    const float* zlrow = zl + (size_t)l * RANKF * CP;
    const float* zrrow = zr + (size_t)l * RANKF * CP;
    float z = 0.f;
#pragma unroll
    for (int r = 0; r < RANKF; ++r) z += zlrow[r * CP + c] + zrrow[r * CP + c];

    float s = z;
#pragma unroll
    for (int off = 32; off >= 1; off >>= 1) s += __shfl_xor(s, off, 64);
    if ((t & 63) == 0) red[t >> 6] = s;
    __syncthreads();
    float mu = (red[half * 2] + red[half * 2 + 1]) * (1.f / 128.f);
    float d = z - mu;
    float sq = d * d;
#pragma unroll
    for (int off = 32; off >= 1; off >>= 1) sq += __shfl_xor(sq, off, 64);
    if ((t & 63) == 0) red[4 + (t >> 6)] = sq;
    __syncthreads();
    float var = (red[4 + half * 2] + red[4 + half * 2 + 1]) * (1.f / 128.f);
    float rstd = rsqrtf(var + 1e-5f);
    float val = d * rstd * g[c] + b[c];
    zn_s[(size_t)l * CP + c] = f2bf(val);
    // key-bias pre-scaled by log2(e): exp(x)=exp2(x*log2e); mask==1 -> 0 exact
    if (c == 0) kb[l] = 1.4426950e9f * (mask[l] - 1.f);
    // Wbias: constant along softmax key axis -> cancels exactly; skipped.
  } else if (bid < 1072) {
    // -------- transpose concat [Wq|Wk|Wv] -> [col][128] bf16 --------
    int c0 = (bid - 1024) * 32;
#pragma unroll
    for (int i = 0; i < 16; ++i) {
      int idx = i * 256 + t;
      int col = idx & 31, kk = idx >> 5;
      int gc = c0 + col;
      float w;
      if (gc < 512)       w = Wq[(size_t)kk * CH + gc];
      else if (gc < 1024) w = Wk[(size_t)kk * CH + gc - 512];
      else                w = Wv[(size_t)kk * CH + gc - 1024];
      tile[kk][col] = w;
    }
    __syncthreads();
#pragma unroll
    for (int i = 0; i < 16; ++i) {
      int idx = i * 256 + t;
      int kk = idx & 127, col = idx >> 7;
      Wt_s[(size_t)(c0 + col) * 128 + kk] = f2bf(tile[kk][col]);
    }
  } else if (bid < 1076) {
    // -------- transpose Wgate -> [col][128] bf16 --------
    int c0 = (bid - 1072) * 32;
#pragma unroll
    for (int i = 0; i < 16; ++i) {
      int idx = i * 256 + t;
      int col = idx & 31, kk = idx >> 5;
      tile[kk][col] = Wg[(size_t)kk * CP + c0 + col];
    }
    __syncthreads();
#pragma unroll
    for (int i = 0; i < 16; ++i) {
      int idx = i * 256 + t;
      int kk = idx & 127, col = idx >> 7;
      Wgt_s[(size_t)(c0 + col) * 128 + kk] = f2bf(tile[kk][col]);
    }
  } else {
    // -------- transpose Wout -> [col][512] bf16 --------
    int bx = bid - 1076;
    int c0 = (bx & 3) * 32, k0 = (bx >> 2) * 128;
#pragma unroll
    for (int i = 0; i < 16; ++i) {
      int idx = i * 256 + t;
      int col = idx & 31, kk = idx >> 5;
      tile[kk][col] = Wout[(size_t)(k0 + kk) * CP + c0 + col];
    }
    __syncthreads();
#pragma unroll
    for (int i = 0; i < 16; ++i) {
      int idx = i * 256 + t;
      int kk = idx & 127, col = idx >> 7;
      Wot_s[(size_t)(c0 + col) * 512 + k0 + kk] = f2bf(tile[kk][col]);
    }
  }
}

// ---------------- K2: QKV projection, 1-pass bf16 MFMA ----------------------
// grid (12, 32), 256 thr = 4 waves; block: 64 rows x 128 cols; K=128 in 4 steps
__global__ __launch_bounds__(256, 4)
void k_proj(const unsigned short* __restrict__ zn_s, const unsigned short* __restrict__ Wt_s,
            const float* __restrict__ bq, const float* __restrict__ bk,
            const float* __restrict__ bv,
            unsigned short* __restrict__ q_s, unsigned short* __restrict__ k_s,
            unsigned short* __restrict__ vt_s) {
  __shared__ unsigned short vtile[128][65];
  int t = threadIdx.x, wid = t >> 6, lane = t & 63, li = lane & 15, g = lane >> 4;
  int cb = blockIdx.x;
  int c0 = cb * 128;
  int rb = blockIdx.y * 64;
  int arow = rb + wid * 16 + li;

  f32x4 acc[8];
#pragma unroll
  for (int i = 0; i < 8; ++i) acc[i] = (f32x4){0.f, 0.f, 0.f, 0.f};

  const unsigned short* ap = zn_s + (size_t)arow * CP;
#pragma unroll
  for (int s = 0; s < 4; ++s) {
    bf16x8 af = *(const bf16x8*)(ap + s * 32 + g * 8);
#pragma unroll
    for (int tt = 0; tt < 8; ++tt) {
      int col = c0 + tt * 16 + li;
      bf16x8 bfr = *(const bf16x8*)(Wt_s + (size_t)col * 128 + s * 32 + g * 8);
      acc[tt] = __builtin_amdgcn_mfma_f32_16x16x32_bf16(af, bfr, acc[tt], 0, 0, 0);
    }
  }

  int mode = cb >> 2;  // 0=q 1=k 2=v
  if (mode == 2) {
#pragma unroll
    for (int tt = 0; tt < 8; ++tt) {
      int colL = tt * 16 + li;
      float bb = bv[c0 - 1024 + colL];
#pragma unroll
      for (int r = 0; r < 4; ++r)
        vtile[colL][wid * 16 + g * 4 + r] = f2bf(acc[tt][r] + bb);
    }
    __syncthreads();
#pragma unroll
    for (int i = 0; i < 32; ++i) {      // 8192 elems: 128 cols x 64 rows
      int idx = i * 256 + t;
      int colL = idx >> 6, rowL = idx & 63;
      vt_s[(size_t)(c0 - 1024 + colL) * L + rb + rowL] = vtile[colL][rowL];
    }
  } else {
#pragma unroll
    for (int tt = 0; tt < 8; ++tt) {
      int col = c0 + tt * 16 + li;
#pragma unroll
      for (int r = 0; r < 4; ++r) {
        int orow = rb + wid * 16 + g * 4 + r;
        float val = acc[tt][r];
        if (mode == 0) {
          // fold 0.125*log2(e) into Q (bf16 rounding is scale-invariant)
          q_s[(size_t)orow * CH + col] = f2bf((val + bq[col]) * 0.18033688f);
        } else {
          k_s[(size_t)orow * CH + col - 512] = f2bf(val + bk[col - 512]);
        }
      }
    }
  }
}

// ---------------- K3: flash attention, swapped-QK^T, 128-key tiles ----------
// QB=128: 8 waves x 16 q-rows; grid 8x16x4 = 512 blocks; 4 barriers/block
#define QB 128
#define KTILE 128
#define NTT (KEYS / KTILE)
#define LK0  0
#define LK1  16384
#define LVT0 32768
#define LVT1 49152
#define LP   65536     // 8 waves x 2048B = 16 KB; total LDS 80 KB

__global__ __launch_bounds__(512, 4)
void k_attn(const unsigned short* __restrict__ qg, const unsigned short* __restrict__ kg,
            const unsigned short* __restrict__ vtg, const float* __restrict__ kbias,
            unsigned short* __restrict__ po, float* __restrict__ pl) {
  __shared__ __align__(16) unsigned char lds[81920];
  int h = blockIdx.x, qblk = blockIdx.y, ksp = blockIdx.z;
  int tid = threadIdx.x, wid = tid >> 6, lane = tid & 63;
  int li = lane & 15, g = lane >> 4;
  int q0 = qblk * QB, hbase = h * HD, kbase = ksp * KEYS;

  // Q fragment: lane holds Q[q=li][d = 8g + 32*h2]  (B-operand layout)
  bf16x8 aq[2];
  {
    const unsigned short* qp = qg + (size_t)(q0 + wid * 16 + li) * CH + hbase + g * 8;
    aq[0] = *(const bf16x8*)(qp);
    aq[1] = *(const bf16x8*)(qp + 32);
  }

  float lsum = 0.f;                       // per-lane: rowsum for q = li
  f32x4 o[4];
#pragma unroll
  for (int t2 = 0; t2 < 4; ++t2) o[t2] = (f32x4){0.f, 0.f, 0.f, 0.f};

  // stage one 128-key tile = 2x 64-key sub-tiles per operand
  auto stage = [&](int buf, int kt) {
    int k0 = kbase + kt * KTILE;
    int row = tid >> 3, c16 = tid & 7;
#pragma unroll
    for (int hh = 0; hh < 2; ++hh) {
      const unsigned short* gpk = kg + (size_t)(k0 + hh * 64 + row) * CH + hbase + ((c16 ^ (row & 7)) << 3);
      __builtin_amdgcn_global_load_lds(
          (const __attribute__((address_space(1))) unsigned int*)(gpk),
          (__attribute__((address_space(3))) unsigned int*)(lds + (buf ? LK1 : LK0) + hh * 8192 + wid * 1024),
          16, 0, 0);
      const unsigned short* gpv = vtg + (size_t)(hbase + row) * L + k0 + hh * 64 + ((c16 ^ (row & 7)) << 3);
      __builtin_amdgcn_global_load_lds(
          (const __attribute__((address_space(1))) unsigned int*)(gpv),
          (__attribute__((address_space(3))) unsigned int*)(lds + (buf ? LVT1 : LVT0) + hh * 8192 + wid * 1024),
          16, 0, 0);
    }
  };

  stage(0, 0);
  __syncthreads();

  for (int kt = 0; kt < NTT; ++kt) {
    int buf = kt & 1;
    if (kt + 1 < NTT) stage(buf ^ 1, kt + 1);

    const unsigned char* Kb = lds + (buf ? LK1 : LK0);
    const unsigned char* Vb = lds + (buf ? LVT1 : LVT0);

#pragma unroll
    for (int hh = 0; hh < 2; ++hh) {
      int k0 = kbase + kt * KTILE + hh * 64;
      const unsigned char* Kbh = Kb + hh * 8192;
      const unsigned char* Vbh = Vb + hh * 8192;

      float4 kbv[4];
#pragma unroll
      for (int tt = 0; tt < 4; ++tt)
        kbv[tt] = *(const float4*)(kbias + k0 + tt * 16 + 4 * g);

      // ---- swapped QK^T: D[key][q], key = 16tt+4g+r (row), q = li (col) ----
      f32x4 s[4];
      __builtin_amdgcn_s_setprio(1);
#pragma unroll
      for (int tt = 0; tt < 4; ++tt) {
        int key = tt * 16 + li;
        f32x4 accs = (f32x4){0.f, 0.f, 0.f, 0.f};
#pragma unroll
        for (int h2 = 0; h2 < 2; ++h2) {
          int c16 = h2 * 4 + g;
          bf16x8 bk = *(const bf16x8*)(Kbh + key * 128 + ((c16 ^ (key & 7)) << 4));
          accs = __builtin_amdgcn_mfma_f32_16x16x32_bf16(bk, aq[h2], accs, 0, 0, 0);
        }
        s[tt] = accs;
      }
      __builtin_amdgcn_s_setprio(0);

      // ---- softmax: Q pre-scaled by 0.125*log2e, kb by log2e -> exp2 ----
      unsigned pk[4][2];
#pragma unroll
      for (int tt = 0; tt < 4; ++tt) {
        float e0 = exp2f(s[tt][0] + kbv[tt].x);
        float e1 = exp2f(s[tt][1] + kbv[tt].y);
        float e2 = exp2f(s[tt][2] + kbv[tt].z);
        float e3 = exp2f(s[tt][3] + kbv[tt].w);
        lsum += (e0 + e1) + (e2 + e3);
        pk[tt][0] = pack2bf(e0, e1);
        pk[tt][1] = pack2bf(e2, e3);
      }

      // ---- P -> per-wave LDS, swizzled u32 writes: P[q=li][key] ----
      unsigned char* Pp = lds + LP + wid * 2048;
#pragma unroll
      for (int tt = 0; tt < 4; ++tt) {
#pragma unroll
        for (int p = 0; p < 2; ++p) {
          int boff = 32 * tt + 8 * g + 4 * p;
          int addr = li * 128 + ((((boff >> 4) ^ (li & 7)) << 4) | (boff & 15));
          *(unsigned*)(Pp + addr) = pk[tt][p];
        }
      }

      // ---- PV: A = P[q=li][k = 8g + 32c], B = V^T; D[q=4g+r][d=t2*16+li] ----
      __builtin_amdgcn_s_setprio(1);
#pragma unroll
      for (int c = 0; c < 2; ++c) {
        int gran = 4 * c + g;
        bf16x8 pa = *(const bf16x8*)(Pp + li * 128 + ((gran ^ (li & 7)) << 4));
#pragma unroll
        for (int t2 = 0; t2 < 4; ++t2) {
          int d = t2 * 16 + li;
          bf16x8 bv2 = *(const bf16x8*)(Vbh + d * 128 + ((gran ^ (d & 7)) << 4));
          o[t2] = __builtin_amdgcn_mfma_f32_16x16x32_bf16(pa, bv2, o[t2], 0, 0, 0);
        }
      }
      __builtin_amdgcn_s_setprio(0);
    }

    __syncthreads();
  }

  // ---- epilogue: reduce lsum over g; redistribute to q=4g+r; store ----
  lsum += __shfl_xor(lsum, 16);
  lsum += __shfl_xor(lsum, 32);
  float rinv[4];
#pragma unroll
  for (int r = 0; r < 4; ++r) rinv[r] = 1.f / __shfl(lsum, 4 * g + r, 16);
#pragma unroll
  for (int t2 = 0; t2 < 4; ++t2) {
#pragma unroll
    for (int r = 0; r < 4; ++r) {
      int qrow = q0 + wid * 16 + 4 * g + r;
      po[((size_t)ksp * L + qrow) * CH + hbase + t2 * 16 + li] = f2bf(o[t2][r] * rinv[r]);
    }
  }
  if (g == 0) {
    int qrow = q0 + wid * 16 + li;
    pl[((size_t)ksp * NH + h) * L + qrow] = lsum;
  }
}

// ---------------- K4: merge + out-proj MFMA + fused gate + broadcast --------
// grid 128 blocks, 256 thr = 4 waves; block: 16 rows x 128 cols
__global__ __launch_bounds__(256, 4)
void k_out(const unsigned short* __restrict__ po, const float* __restrict__ pl,
           const unsigned short* __restrict__ Wot_s, const float* __restrict__ bout,
           const unsigned short* __restrict__ zn_s, const unsigned short* __restrict__ Wgt_s,
           const float* __restrict__ bg, float* __restrict__ out) {
  __shared__ __align__(16) unsigned short atile[16 * 512];
  unsigned char* ab = (unsigned char*)atile;
  int t = threadIdx.x, wid = t >> 6, lane = t & 63, li = lane & 15, g = lane >> 4;
  int r0 = blockIdx.x * 16;

  int col8 = lane * 8;
  int h = col8 >> 6;
#pragma unroll
  for (int i = 0; i < 4; ++i) {
    int rowL = wid * 4 + i;
    int row = r0 + rowL;
    float w[4], wsum = 0.f;
#pragma unroll
    for (int s2 = 0; s2 < 4; ++s2) {
      w[s2] = pl[((size_t)s2 * NH + h) * L + row];
      wsum += w[s2];
    }
    float rinv = 1.f / wsum;
    float accv[8];
#pragma unroll
    for (int j = 0; j < 8; ++j) accv[j] = 0.f;
#pragma unroll
    for (int s2 = 0; s2 < 4; ++s2) {
      bf16x8 pv = *(const bf16x8*)(po + ((size_t)s2 * L + row) * CH + col8);
      float ww = w[s2];
#pragma unroll
      for (int j = 0; j < 8; ++j) accv[j] += ww * bf2f((unsigned short)pv[j]);
    }
    bf16x8 packed;
#pragma unroll
    for (int j = 0; j < 8; ++j) packed[j] = (short)f2bf(accv[j] * rinv);
    int byteoff = (rowL * 1024 + col8 * 2) ^ ((rowL & 7) << 4);
    *(bf16x8*)(ab + byteoff) = packed;
  }
  __syncthreads();

  // GEMM phase: out-proj (K=512) + gate (K=128); wave covers cols [w*32,w*32+32)
  f32x4 acc[2], gacc[2];
#pragma unroll
  for (int i = 0; i < 2; ++i) {
    acc[i] = (f32x4){0.f, 0.f, 0.f, 0.f};
    gacc[i] = (f32x4){0.f, 0.f, 0.f, 0.f};
  }
#pragma unroll
  for (int s = 0; s < 16; ++s) {
    int abyte = (li * 1024 + (s * 32 + g * 8) * 2) ^ ((li & 7) << 4);
    bf16x8 af = *(const bf16x8*)(ab + abyte);
#pragma unroll
    for (int tt = 0; tt < 2; ++tt) {
      int col = wid * 32 + tt * 16 + li;
      bf16x8 bfr = *(const bf16x8*)(Wot_s + (size_t)col * 512 + s * 32 + g * 8);
      acc[tt] = __builtin_amdgcn_mfma_f32_16x16x32_bf16(af, bfr, acc[tt], 0, 0, 0);
    }
  }
#pragma unroll
  for (int s = 0; s < 4; ++s) {
    bf16x8 af = *(const bf16x8*)(zn_s + (size_t)(r0 + li) * CP + s * 32 + g * 8);
#pragma unroll
    for (int tt = 0; tt < 2; ++tt) {
      int col = wid * 32 + tt * 16 + li;
      bf16x8 bfr = *(const bf16x8*)(Wgt_s + (size_t)col * 128 + s * 32 + g * 8);
      gacc[tt] = __builtin_amdgcn_mfma_f32_16x16x32_bf16(af, bfr, gacc[tt], 0, 0, 0);
    }
  }

#pragma unroll
  for (int tt = 0; tt < 2; ++tt) {
    int col = wid * 32 + tt * 16 + li;
    float bb = bout[col];
    float gb = bg[col];
#pragma unroll
    for (int r = 0; r < 4; ++r) {
      int row = r0 + g * 4 + r;
      float gatev = 1.f / (1.f + __expf(-(gacc[tt][r] + gb)));
      float val = (acc[tt][r] + bb) * gatev * 0.25f;
#pragma unroll
      for (int rk = 0; rk < 4; ++rk)
        out[(size_t)(row * 4 + rk) * CP + col] = val;
    }
  }
  float4 z = {0.f, 0.f, 0.f, 0.f};
  float4* orp = (float4*)(out + (size_t)L * RANKF * CP + (size_t)r0 * 4 * CP);
#pragma unroll
  for (int i = 0; i < 8; ++i) orp[i * 256 + t] = z;
}

extern "C" void kernel_launch(void* const* d_in, const int* in_sizes, int n_in,
                              void* d_out, int out_size, void* d_ws, size_t ws_size,
                              hipStream_t stream) {
  const float* zl   = (const float*)d_in[0];
  const float* zr   = (const float*)d_in[1];
  const float* mask = (const float*)d_in[2];
  const float* lng  = (const float*)d_in[3];
  const float* lnb  = (const float*)d_in[4];
  const float* Wq   = (const float*)d_in[5];
  const float* bq   = (const float*)d_in[6];
  const float* Wk   = (const float*)d_in[7];
  const float* bk   = (const float*)d_in[8];
  const float* Wv   = (const float*)d_in[9];
  const float* bv   = (const float*)d_in[10];
  // d_in[11] = Wbias: softmax-invariant -> unused
  const float* Wout = (const float*)d_in[12];
  const float* bout = (const float*)d_in[13];
  const float* Wg   = (const float*)d_in[14];
  const float* bg   = (const float*)d_in[15];
  float* out = (float*)d_out;
  unsigned char* ws = (unsigned char*)d_ws;

  unsigned short* zn_s  = (unsigned short*)(ws + O_ZNS);
  unsigned short* Wt_s  = (unsigned short*)(ws + O_WTS);
  unsigned short* Wgt_s = (unsigned short*)(ws + O_WGT);
  unsigned short* Wot_s = (unsigned short*)(ws + O_WOTS);
  unsigned short* q_s   = (unsigned short*)(ws + O_QS);
  unsigned short* k_s   = (unsigned short*)(ws + O_KS2);
  unsigned short* vt_s  = (unsigned short*)(ws + O_VTS);
  float* kb   = (float*)(ws + O_KB);
  unsigned short* po = (unsigned short*)(ws + O_PO);
  float* pl   = (float*)(ws + O_PL);

  k_prep<<<dim3(1092),       dim3(256), 0, stream>>>(zl, zr, mask, lng, lnb,
                                                     Wq, Wk, Wv, Wg, Wout,
                                                     zn_s, kb, Wt_s, Wgt_s, Wot_s);
  k_proj<<<dim3(12, 32),     dim3(256), 0, stream>>>(zn_s, Wt_s, bq, bk, bv,
                                                     q_s, k_s, vt_s);
  k_attn<<<dim3(NH, L/QB, KS), dim3(512), 0, stream>>>(q_s, k_s, vt_s, kb, po, pl);
  k_out <<<dim3(L/16),       dim3(256), 0, stream>>>(po, pl, Wot_s, bout,
                                                     zn_s, Wgt_s, bg, out);
}

// Round 18
// 57.714 us; speedup vs baseline: 4.2180x; 1.0382x over previous
//
#include <hip/hip_runtime.h>
#include <math.h>

#define L 2048
#define CP 128
#define CH 512
#define NH 8
#define HD 64
#define RANKF 4
#define KS 4
#define KEYS (L / KS)

typedef __attribute__((ext_vector_type(8))) short bf16x8;
typedef __attribute__((ext_vector_type(4))) float f32x4;

// ws byte offsets
#define O_ZNS   0u         // [2048][128] bf16      512 KB
#define O_WTS   524288u    // [1536][128] bf16      384 KB  (Wq|Wk|Wv)^T
#define O_WGT   917504u    // [128][128]  bf16       32 KB  Wgate^T
#define O_WOTS  950272u    // [128][512]  bf16      128 KB  Wout^T
#define O_QS    1081344u   // [2048][512] bf16        2 MB
#define O_KS2   3178496u   // [2048][512] bf16        2 MB
#define O_VTS   5275648u   // [512][2048] bf16        2 MB
#define O_KB    7372800u   // [2048] f32              8 KB
#define O_PO    7380992u   // [4][2048][512] bf16     8 MB
#define O_PL    15769600u  // [4][8][2048] f32      256 KB

__device__ __forceinline__ unsigned short f2bf(float f) {
  union { float f; unsigned u; } x; x.f = f;
  unsigned r = x.u + 0x7fffu + ((x.u >> 16) & 1u);
  return (unsigned short)(r >> 16);
}
__device__ __forceinline__ float bf2f(unsigned short h) {
  union { unsigned u; float f; } x; x.u = ((unsigned)h) << 16;
  return x.f;
}
// pack (lo, hi) -> u32 with lo in bits [15:0]; bit-level, validated rounding
__device__ __forceinline__ unsigned pack2bf(float lo, float hi) {
  return (unsigned)f2bf(lo) | ((unsigned)f2bf(hi) << 16);
}

// ---------------- K1: fused prep (LN | Wqkv^T | Wgate^T | Wout^T) -----------
// grid: [0,1024) LN 2 rows | [1024,1072) Wqkv | [1072,1076) Wgate | [1076,1092) Wout
__global__ __launch_bounds__(256, 4)
void k_prep(const float* __restrict__ zl, const float* __restrict__ zr,
            const float* __restrict__ mask,
            const float* __restrict__ g, const float* __restrict__ b,
            const float* __restrict__ Wq, const float* __restrict__ Wk,
            const float* __restrict__ Wv, const float* __restrict__ Wg,
            const float* __restrict__ Wout,
            unsigned short* __restrict__ zn_s, float* __restrict__ kb,
            unsigned short* __restrict__ Wt_s, unsigned short* __restrict__ Wgt_s,
            unsigned short* __restrict__ Wot_s) {
  __shared__ float tile[128][33];
  __shared__ float red[8];
  int bid = blockIdx.x;
  int t = threadIdx.x;

  if (bid < 1024) {
    // -------- LayerNorm, 2 rows per block; bf16 output --------
    int half = t >> 7, c = t & 127;
    int l = bid * 2 + half;
    const float* zlrow = zl + (size_t)l * RANKF * CP;
    const float* zrrow = zr + (size_t)l * RANKF * CP;
    float z = 0.f;
#pragma unroll
    for (int r = 0; r < RANKF; ++r) z += zlrow[r * CP + c] + zrrow[r * CP + c];

    float s = z;
#pragma unroll
    for (int off = 32; off >= 1; off >>= 1) s += __shfl_xor(s, off, 64);
    if ((t & 63) == 0) red[t >> 6] = s;
    __syncthreads();
    float mu = (red[half * 2] + red[half * 2 + 1]) * (1.f / 128.f);
    float d = z - mu;
    float sq = d * d;
#pragma unroll
    for (int off = 32; off >= 1; off >>= 1) sq += __shfl_xor(sq, off, 64);
    if ((t & 63) == 0) red[4 + (t >> 6)] = sq;
    __syncthreads();
    float var = (red[4 + half * 2] + red[4 + half * 2 + 1]) * (1.f / 128.f);
    float rstd = rsqrtf(var + 1e-5f);
    float val = d * rstd * g[c] + b[c];
    zn_s[(size_t)l * CP + c] = f2bf(val);
    if (c == 0) kb[l] = 1e9f * (mask[l] - 1.f);
    // Wbias: constant along softmax key axis -> cancels exactly; skipped.
  } else if (bid < 1072) {
    // -------- transpose concat [Wq|Wk|Wv] -> [col][128] bf16 --------
    int c0 = (bid - 1024) * 32;
#pragma unroll
    for (int i = 0; i < 16; ++i) {
      int idx = i * 256 + t;
      int col = idx & 31, kk = idx >> 5;
      int gc = c0 + col;
      float w;
      if (gc < 512)       w = Wq[(size_t)kk * CH + gc];
      else if (gc < 1024) w = Wk[(size_t)kk * CH + gc - 512];
      else                w = Wv[(size_t)kk * CH + gc - 1024];
      tile[kk][col] = w;
    }
    __syncthreads();
#pragma unroll
    for (int i = 0; i < 16; ++i) {
      int idx = i * 256 + t;
      int kk = idx & 127, col = idx >> 7;
      Wt_s[(size_t)(c0 + col) * 128 + kk] = f2bf(tile[kk][col]);
    }
  } else if (bid < 1076) {
    // -------- transpose Wgate -> [col][128] bf16 --------
    int c0 = (bid - 1072) * 32;
#pragma unroll
    for (int i = 0; i < 16; ++i) {
      int idx = i * 256 + t;
      int col = idx & 31, kk = idx >> 5;
      tile[kk][col] = Wg[(size_t)kk * CP + c0 + col];
    }
    __syncthreads();
#pragma unroll
    for (int i = 0; i < 16; ++i) {
      int idx = i * 256 + t;
      int kk = idx & 127, col = idx >> 7;
      Wgt_s[(size_t)(c0 + col) * 128 + kk] = f2bf(tile[kk][col]);
    }
  } else {
    // -------- transpose Wout -> [col][512] bf16 --------
    int bx = bid - 1076;
    int c0 = (bx & 3) * 32, k0 = (bx >> 2) * 128;
#pragma unroll
    for (int i = 0; i < 16; ++i) {
      int idx = i * 256 + t;
      int col = idx & 31, kk = idx >> 5;
      tile[kk][col] = Wout[(size_t)(k0 + kk) * CP + c0 + col];
    }
    __syncthreads();
#pragma unroll
    for (int i = 0; i < 16; ++i) {
      int idx = i * 256 + t;
      int kk = idx & 127, col = idx >> 7;
      Wot_s[(size_t)(c0 + col) * 512 + k0 + kk] = f2bf(tile[kk][col]);
    }
  }
}

// ---------------- K2: QKV projection, 1-pass bf16 MFMA ----------------------
// grid (12, 32), 256 thr = 4 waves; block: 64 rows x 128 cols; K=128 in 4 steps
__global__ __launch_bounds__(256, 4)
void k_proj(const unsigned short* __restrict__ zn_s, const unsigned short* __restrict__ Wt_s,
            const float* __restrict__ bq, const float* __restrict__ bk,
            const float* __restrict__ bv,
            unsigned short* __restrict__ q_s, unsigned short* __restrict__ k_s,
            unsigned short* __restrict__ vt_s) {
  __shared__ unsigned short vtile[128][65];
  int t = threadIdx.x, wid = t >> 6, lane = t & 63, li = lane & 15, g = lane >> 4;
  int cb = blockIdx.x;
  int c0 = cb * 128;
  int rb = blockIdx.y * 64;
  int arow = rb + wid * 16 + li;

  f32x4 acc[8];
#pragma unroll
  for (int i = 0; i < 8; ++i) acc[i] = (f32x4){0.f, 0.f, 0.f, 0.f};

  const unsigned short* ap = zn_s + (size_t)arow * CP;
#pragma unroll
  for (int s = 0; s < 4; ++s) {
    bf16x8 af = *(const bf16x8*)(ap + s * 32 + g * 8);
#pragma unroll
    for (int tt = 0; tt < 8; ++tt) {
      int col = c0 + tt * 16 + li;
      bf16x8 bfr = *(const bf16x8*)(Wt_s + (size_t)col * 128 + s * 32 + g * 8);
      acc[tt] = __builtin_amdgcn_mfma_f32_16x16x32_bf16(af, bfr, acc[tt], 0, 0, 0);
    }
  }

  int mode = cb >> 2;  // 0=q 1=k 2=v
  if (mode == 2) {
#pragma unroll
    for (int tt = 0; tt < 8; ++tt) {
      int colL = tt * 16 + li;
      float bb = bv[c0 - 1024 + colL];
#pragma unroll
      for (int r = 0; r < 4; ++r)
        vtile[colL][wid * 16 + g * 4 + r] = f2bf(acc[tt][r] + bb);
    }
    __syncthreads();
#pragma unroll
    for (int i = 0; i < 32; ++i) {      // 8192 elems: 128 cols x 64 rows
      int idx = i * 256 + t;
      int colL = idx >> 6, rowL = idx & 63;
      vt_s[(size_t)(c0 - 1024 + colL) * L + rb + rowL] = vtile[colL][rowL];
    }
  } else {
#pragma unroll
    for (int tt = 0; tt < 8; ++tt) {
      int col = c0 + tt * 16 + li;
#pragma unroll
      for (int r = 0; r < 4; ++r) {
        int orow = rb + wid * 16 + g * 4 + r;
        float val = acc[tt][r];
        if (mode == 0) {
          q_s[(size_t)orow * CH + col] = f2bf(val + bq[col]);
        } else {
          k_s[(size_t)orow * CH + col - 512] = f2bf(val + bk[col - 512]);
        }
      }
    }
  }
}

// ---------------- K3: flash attention, swapped-QK^T, 128-key tiles ----------
// QB=128: 8 waves x 16 q-rows; grid 8x16x4 = 512 blocks; 4 barriers/block
#define QB 128
#define KTILE 128
#define NTT (KEYS / KTILE)
#define LK0  0
#define LK1  16384
#define LVT0 32768
#define LVT1 49152
#define LP   65536     // 8 waves x 2048B = 16 KB; total LDS 80 KB

__global__ __launch_bounds__(512, 4)
void k_attn(const unsigned short* __restrict__ qg, const unsigned short* __restrict__ kg,
            const unsigned short* __restrict__ vtg, const float* __restrict__ kbias,
            unsigned short* __restrict__ po, float* __restrict__ pl) {
  __shared__ __align__(16) unsigned char lds[81920];
  int h = blockIdx.x, qblk = blockIdx.y, ksp = blockIdx.z;
  int tid = threadIdx.x, wid = tid >> 6, lane = tid & 63;
  int li = lane & 15, g = lane >> 4;
  int q0 = qblk * QB, hbase = h * HD, kbase = ksp * KEYS;

  // Q fragment: lane holds Q[q=li][d = 8g + 32*h2]  (B-operand layout)
  bf16x8 aq[2];
  {
    const unsigned short* qp = qg + (size_t)(q0 + wid * 16 + li) * CH + hbase + g * 8;
    aq[0] = *(const bf16x8*)(qp);
    aq[1] = *(const bf16x8*)(qp + 32);
  }

  float lsum = 0.f;                       // per-lane: rowsum for q = li
  f32x4 o[4];
#pragma unroll
  for (int t2 = 0; t2 < 4; ++t2) o[t2] = (f32x4){0.f, 0.f, 0.f, 0.f};

  // stage one 128-key tile = 2x 64-key sub-tiles per operand
  auto stage = [&](int buf, int kt) {
    int k0 = kbase + kt * KTILE;
    int row = tid >> 3, c16 = tid & 7;
#pragma unroll
    for (int hh = 0; hh < 2; ++hh) {
      const unsigned short* gpk = kg + (size_t)(k0 + hh * 64 + row) * CH + hbase + ((c16 ^ (row & 7)) << 3);
      __builtin_amdgcn_global_load_lds(
          (const __attribute__((address_space(1))) unsigned int*)(gpk),
          (__attribute__((address_space(3))) unsigned int*)(lds + (buf ? LK1 : LK0) + hh * 8192 + wid * 1024),
          16, 0, 0);
      const unsigned short* gpv = vtg + (size_t)(hbase + row) * L + k0 + hh * 64 + ((c16 ^ (row & 7)) << 3);
      __builtin_amdgcn_global_load_lds(
          (const __attribute__((address_space(1))) unsigned int*)(gpv),
          (__attribute__((address_space(3))) unsigned int*)(lds + (buf ? LVT1 : LVT0) + hh * 8192 + wid * 1024),
          16, 0, 0);
    }
  };

  stage(0, 0);
  __syncthreads();

  for (int kt = 0; kt < NTT; ++kt) {
    int buf = kt & 1;
    if (kt + 1 < NTT) stage(buf ^ 1, kt + 1);

    const unsigned char* Kb = lds + (buf ? LK1 : LK0);
    const unsigned char* Vb = lds + (buf ? LVT1 : LVT0);

#pragma unroll
    for (int hh = 0; hh < 2; ++hh) {
      int k0 = kbase + kt * KTILE + hh * 64;
      const unsigned char* Kbh = Kb + hh * 8192;
      const unsigned char* Vbh = Vb + hh * 8192;

      float4 kbv[4];
#pragma unroll
      for (int tt = 0; tt < 4; ++tt)
        kbv[tt] = *(const float4*)(kbias + k0 + tt * 16 + 4 * g);

      // ---- swapped QK^T: D[key][q], key = 16tt+4g+r (row), q = li (col) ----
      f32x4 s[4];
      __builtin_amdgcn_s_setprio(1);
#pragma unroll
      for (int tt = 0; tt < 4; ++tt) {
        int key = tt * 16 + li;
        f32x4 accs = (f32x4){0.f, 0.f, 0.f, 0.f};
#pragma unroll
        for (int h2 = 0; h2 < 2; ++h2) {
          int c16 = h2 * 4 + g;
          bf16x8 bk = *(const bf16x8*)(Kbh + key * 128 + ((c16 ^ (key & 7)) << 4));
          accs = __builtin_amdgcn_mfma_f32_16x16x32_bf16(bk, aq[h2], accs, 0, 0, 0);
        }
        s[tt] = accs;
      }
      __builtin_amdgcn_s_setprio(0);

      // ---- softmax: per-lane scalar denominator; pack P to bf16 pairs ----
      unsigned pk[4][2];
#pragma unroll
      for (int tt = 0; tt < 4; ++tt) {
        float e0 = __expf(s[tt][0] * 0.125f + kbv[tt].x);
        float e1 = __expf(s[tt][1] * 0.125f + kbv[tt].y);
        float e2 = __expf(s[tt][2] * 0.125f + kbv[tt].z);
        float e3 = __expf(s[tt][3] * 0.125f + kbv[tt].w);
        lsum += (e0 + e1) + (e2 + e3);
        pk[tt][0] = pack2bf(e0, e1);
        pk[tt][1] = pack2bf(e2, e3);
      }

      // ---- P -> per-wave LDS, swizzled u32 writes: P[q=li][key] ----
      unsigned char* Pp = lds + LP + wid * 2048;
#pragma unroll
      for (int tt = 0; tt < 4; ++tt) {
#pragma unroll
        for (int p = 0; p < 2; ++p) {
          int boff = 32 * tt + 8 * g + 4 * p;
          int addr = li * 128 + ((((boff >> 4) ^ (li & 7)) << 4) | (boff & 15));
          *(unsigned*)(Pp + addr) = pk[tt][p];
        }
      }

      // ---- PV: A = P[q=li][k = 8g + 32c], B = V^T; D[q=4g+r][d=t2*16+li] ----
      __builtin_amdgcn_s_setprio(1);
#pragma unroll
      for (int c = 0; c < 2; ++c) {
        int gran = 4 * c + g;
        bf16x8 pa = *(const bf16x8*)(Pp + li * 128 + ((gran ^ (li & 7)) << 4));
#pragma unroll
        for (int t2 = 0; t2 < 4; ++t2) {
          int d = t2 * 16 + li;
          bf16x8 bv2 = *(const bf16x8*)(Vbh + d * 128 + ((gran ^ (d & 7)) << 4));
          o[t2] = __builtin_amdgcn_mfma_f32_16x16x32_bf16(pa, bv2, o[t2], 0, 0, 0);
        }
      }
      __builtin_amdgcn_s_setprio(0);
    }

    __syncthreads();
  }

  // ---- epilogue: reduce lsum over g; redistribute to q=4g+r; store ----
  lsum += __shfl_xor(lsum, 16);
  lsum += __shfl_xor(lsum, 32);
  float rinv[4];
#pragma unroll
  for (int r = 0; r < 4; ++r) rinv[r] = 1.f / __shfl(lsum, 4 * g + r, 16);
#pragma unroll
  for (int t2 = 0; t2 < 4; ++t2) {
#pragma unroll
    for (int r = 0; r < 4; ++r) {
      int qrow = q0 + wid * 16 + 4 * g + r;
      po[((size_t)ksp * L + qrow) * CH + hbase + t2 * 16 + li] = f2bf(o[t2][r] * rinv[r]);
    }
  }
  if (g == 0) {
    int qrow = q0 + wid * 16 + li;
    pl[((size_t)ksp * NH + h) * L + qrow] = lsum;
  }
}

// ---------------- K4: merge + out-proj MFMA + fused gate + broadcast --------
// grid 128 blocks, 256 thr = 4 waves; block: 16 rows x 128 cols
__global__ __launch_bounds__(256, 4)
void k_out(const unsigned short* __restrict__ po, const float* __restrict__ pl,
           const unsigned short* __restrict__ Wot_s, const float* __restrict__ bout,
           const unsigned short* __restrict__ zn_s, const unsigned short* __restrict__ Wgt_s,
           const float* __restrict__ bg, float* __restrict__ out) {
  __shared__ __align__(16) unsigned short atile[16 * 512];
  unsigned char* ab = (unsigned char*)atile;
  int t = threadIdx.x, wid = t >> 6, lane = t & 63, li = lane & 15, g = lane >> 4;
  int r0 = blockIdx.x * 16;

  int col8 = lane * 8;
  int h = col8 >> 6;
#pragma unroll
  for (int i = 0; i < 4; ++i) {
    int rowL = wid * 4 + i;
    int row = r0 + rowL;
    float w[4], wsum = 0.f;
#pragma unroll
    for (int s2 = 0; s2 < 4; ++s2) {
      w[s2] = pl[((size_t)s2 * NH + h) * L + row];
      wsum += w[s2];
    }
    float rinv = 1.f / wsum;
    float accv[8];
#pragma unroll
    for (int j = 0; j < 8; ++j) accv[j] = 0.f;
#pragma unroll
    for (int s2 = 0; s2 < 4; ++s2) {
      bf16x8 pv = *(const bf16x8*)(po + ((size_t)s2 * L + row) * CH + col8);
      float ww = w[s2];
#pragma unroll
      for (int j = 0; j < 8; ++j) accv[j] += ww * bf2f((unsigned short)pv[j]);
    }
    bf16x8 packed;
#pragma unroll
    for (int j = 0; j < 8; ++j) packed[j] = (short)f2bf(accv[j] * rinv);
    int byteoff = (rowL * 1024 + col8 * 2) ^ ((rowL & 7) << 4);
    *(bf16x8*)(ab + byteoff) = packed;
  }
  __syncthreads();

  // GEMM phase: out-proj (K=512) + gate (K=128); wave covers cols [w*32,w*32+32)
  f32x4 acc[2], gacc[2];
#pragma unroll
  for (int i = 0; i < 2; ++i) {
    acc[i] = (f32x4){0.f, 0.f, 0.f, 0.f};
    gacc[i] = (f32x4){0.f, 0.f, 0.f, 0.f};
  }
#pragma unroll
  for (int s = 0; s < 16; ++s) {
    int abyte = (li * 1024 + (s * 32 + g * 8) * 2) ^ ((li & 7) << 4);
    bf16x8 af = *(const bf16x8*)(ab + abyte);
#pragma unroll
    for (int tt = 0; tt < 2; ++tt) {
      int col = wid * 32 + tt * 16 + li;
      bf16x8 bfr = *(const bf16x8*)(Wot_s + (size_t)col * 512 + s * 32 + g * 8);
      acc[tt] = __builtin_amdgcn_mfma_f32_16x16x32_bf16(af, bfr, acc[tt], 0, 0, 0);
    }
  }
#pragma unroll
  for (int s = 0; s < 4; ++s) {
    bf16x8 af = *(const bf16x8*)(zn_s + (size_t)(r0 + li) * CP + s * 32 + g * 8);
#pragma unroll
    for (int tt = 0; tt < 2; ++tt) {
      int col = wid * 32 + tt * 16 + li;
      bf16x8 bfr = *(const bf16x8*)(Wgt_s + (size_t)col * 128 + s * 32 + g * 8);
      gacc[tt] = __builtin_amdgcn_mfma_f32_16x16x32_bf16(af, bfr, gacc[tt], 0, 0, 0);
    }
  }

#pragma unroll
  for (int tt = 0; tt < 2; ++tt) {
    int col = wid * 32 + tt * 16 + li;
    float bb = bout[col];
    float gb = bg[col];
#pragma unroll
    for (int r = 0; r < 4; ++r) {
      int row = r0 + g * 4 + r;
      float gatev = 1.f / (1.f + __expf(-(gacc[tt][r] + gb)));
      float val = (acc[tt][r] + bb) * gatev * 0.25f;
#pragma unroll
      for (int rk = 0; rk < 4; ++rk)
        out[(size_t)(row * 4 + rk) * CP + col] = val;
    }
  }
  float4 z = {0.f, 0.f, 0.f, 0.f};
  float4* orp = (float4*)(out + (size_t)L * RANKF * CP + (size_t)r0 * 4 * CP);
#pragma unroll
  for (int i = 0; i < 8; ++i) orp[i * 256 + t] = z;
}

extern "C" void kernel_launch(void* const* d_in, const int* in_sizes, int n_in,
                              void* d_out, int out_size, void* d_ws, size_t ws_size,
                              hipStream_t stream) {
  const float* zl   = (const float*)d_in[0];
  const float* zr   = (const float*)d_in[1];
  const float* mask = (const float*)d_in[2];
  const float* lng  = (const float*)d_in[3];
  const float* lnb  = (const float*)d_in[4];
  const float* Wq   = (const float*)d_in[5];
  const float* bq   = (const float*)d_in[6];
  const float* Wk   = (const float*)d_in[7];
  const float* bk   = (const float*)d_in[8];
  const float* Wv   = (const float*)d_in[9];
  const float* bv   = (const float*)d_in[10];
  // d_in[11] = Wbias: softmax-invariant -> unused
  const float* Wout = (const float*)d_in[12];
  const float* bout = (const float*)d_in[13];
  const float* Wg   = (const float*)d_in[14];
  const float* bg   = (const float*)d_in[15];
  float* out = (float*)d_out;
  unsigned char* ws = (unsigned char*)d_ws;

  unsigned short* zn_s  = (unsigned short*)(ws + O_ZNS);
  unsigned short* Wt_s  = (unsigned short*)(ws + O_WTS);
  unsigned short* Wgt_s = (unsigned short*)(ws + O_WGT);
  unsigned short* Wot_s = (unsigned short*)(ws + O_WOTS);
  unsigned short* q_s   = (unsigned short*)(ws + O_QS);
  unsigned short* k_s   = (unsigned short*)(ws + O_KS2);
  unsigned short* vt_s  = (unsigned short*)(ws + O_VTS);
  float* kb   = (float*)(ws + O_KB);
  unsigned short* po = (unsigned short*)(ws + O_PO);
  float* pl   = (float*)(ws + O_PL);

  k_prep<<<dim3(1092),       dim3(256), 0, stream>>>(zl, zr, mask, lng, lnb,
                                                     Wq, Wk, Wv, Wg, Wout,
                                                     zn_s, kb, Wt_s, Wgt_s, Wot_s);
  k_proj<<<dim3(12, 32),     dim3(256), 0, stream>>>(zn_s, Wt_s, bq, bk, bv,
                                                     q_s, k_s, vt_s);
  k_attn<<<dim3(NH, L/QB, KS), dim3(512), 0, stream>>>(q_s, k_s, vt_s, kb, po, pl);
  k_out <<<dim3(L/16),       dim3(256), 0, stream>>>(po, pl, Wot_s, bout,
                                                     zn_s, Wgt_s, bg, out);
}